// Round 1
// baseline (400.641 us; speedup 1.0000x reference)
//
#include <hip/hip_runtime.h>
#include <math.h>

#define LTOK 8192
#define DDIM 512
#define HDIM 2048
#define NPART 32
#define BM 128
#define BN 128
#define BK 64
#define PW 1280
#define PTILES (PW / BN)

typedef float f32x4 __attribute__((ext_vector_type(4)));
typedef short s16x8 __attribute__((ext_vector_type(8)));

static __device__ __forceinline__ short f2bf(float f) {
    union { float f; unsigned u; } v; v.f = f;
    unsigned r = (v.u + 0x7fffu + ((v.u >> 16) & 1u)) >> 16;
    return (short)r;
}

// bijective XCD swizzles (require GX*GY % 8 == 0; all our grids satisfy).
template<int GX, int GY>
__device__ __forceinline__ void swz_xslow(int& x, int& y) {
    constexpr int cpx = (GX * GY) >> 3;
    const int orig = blockIdx.y * GX + blockIdx.x;
    const int lg = (orig & 7) * cpx + (orig >> 3);
    x = lg / GY;
    y = lg - x * GY;
}
template<int GX, int GY>
__device__ __forceinline__ void swz_yslow(int& x, int& y) {
    constexpr int cpx = (GX * GY) >> 3;
    const int orig = blockIdx.y * GX + blockIdx.x;
    const int lg = (orig & 7) * cpx + (orig >> 3);
    y = lg / GX;
    x = lg - y * GX;
}

// ---------------- column-LN stats (deterministic two-stage) ----------------
__global__ void ln_stats_partial(const float* __restrict__ X,
                                 float* __restrict__ psum, float* __restrict__ psumsq) {
    int c = threadIdx.x;
    int b = blockIdx.x;
    const float* p = X + (size_t)b * 256 * DDIM + c;
    float s = 0.f, s2 = 0.f;
    for (int r = 0; r < 256; ++r) {
        float v = p[(size_t)r * DDIM];
        s += v; s2 += v * v;
    }
    psum[b * DDIM + c] = s;
    psumsq[b * DDIM + c] = s2;
}

__global__ void ln_stats_final(const float* __restrict__ psum, const float* __restrict__ psumsq,
                               float* __restrict__ mu, float* __restrict__ rstd) {
    int c = threadIdx.x;
    float s = 0.f, s2 = 0.f;
    for (int b = 0; b < 32; ++b) { s += psum[b * DDIM + c]; s2 += psumsq[b * DDIM + c]; }
    float m = s / (float)LTOK;
    float var = s2 / (float)LTOK - m * m;
    mu[c] = m;
    rstd[c] = rsqrtf(var + 1e-6f);
}

// ---------------- elementwise LN apply -> bf16 ----------------
__global__ void ln_apply_bf16(const float* __restrict__ X,
                              const float* __restrict__ mu, const float* __restrict__ rstd,
                              short* __restrict__ out) {
    int t = blockIdx.x * 256 + threadIdx.x;
    int base = t * 4;
    int c = base & (DDIM - 1);
    float4 v = *(const float4*)(X + base);
    short4 o;
    o.x = f2bf((v.x - mu[c + 0]) * rstd[c + 0]);
    o.y = f2bf((v.y - mu[c + 1]) * rstd[c + 1]);
    o.z = f2bf((v.z - mu[c + 2]) * rstd[c + 2]);
    o.w = f2bf((v.w - mu[c + 3]) * rstd[c + 3]);
    *(short4*)(out + base) = o;
}

// ---------------- weight transpose fp32 [R][ldw] -> bf16 WT [N][R] ----------------
__global__ void transpose_w(const float* __restrict__ W, int ldw, int n0,
                            short* __restrict__ WT, int R) {
    __shared__ short t[32][33];
    int nb = n0 + blockIdx.x * 32;
    int rb = blockIdx.y * 32;
    int tx = threadIdx.x & 31, ty = threadIdx.x >> 5;
    for (int rr = ty; rr < 32; rr += 8)
        t[rr][tx] = f2bf(W[(size_t)(rb + rr) * ldw + nb + tx]);
    __syncthreads();
    for (int rr = ty; rr < 32; rr += 8)
        WT[(size_t)(nb - n0 + rr) * R + rb + tx] = t[tx][rr];
}

// ---------------- bf16 transpose of xcat: xbT[d][j] ----------------
__global__ void transpose_bf16(const float* __restrict__ X, short* __restrict__ XT) {
    __shared__ short t[32][33];
    int c0 = blockIdx.x * 32;
    int r0 = blockIdx.y * 32;
    int tx = threadIdx.x & 31, ty = threadIdx.x >> 5;
    for (int rr = ty; rr < 32; rr += 8)
        t[rr][tx] = f2bf(X[(size_t)(r0 + rr) * DDIM + c0 + tx]);
    __syncthreads();
    for (int rr = ty; rr < 32; rr += 8)
        XT[(size_t)(c0 + rr) * LTOK + r0 + tx] = t[tx][rr];
}

// ---------------- segment first-row table + second output ----------------
__global__ void seg_begin_k(const int* __restrict__ sep, int* __restrict__ begin,
                            float* __restrict__ out2) {
    int i = blockIdx.x * 256 + threadIdx.x;
    if (i < LTOK) {
        if (i == 0 || sep[i] != sep[i - 1]) begin[sep[i]] = i;
        out2[i] = (float)sep[i];
    }
}

// ---------------- staging (m97 structure): 256-thread ----------------
__device__ __forceinline__ void stage_tile(const short* __restrict__ src, int lda,
                                           short* lds, int tid) {
    const int wave = tid >> 6;
    const int lane = tid & 63;
    #pragma unroll
    for (int u = 0; u < 4; ++u) {
        const int c = wave * 64 + u * 256 + lane;   // 16B chunk index, 0..1023
        const short* g = src + (size_t)(c >> 3) * lda + (c & 7) * 8;
        short* l = lds + (size_t)(wave * 64 + u * 256) * 8;  // wave-uniform base
        __builtin_amdgcn_global_load_lds(
            (const __attribute__((address_space(1))) unsigned int*)g,
            (__attribute__((address_space(3))) unsigned int*)l,
            16, 0, 0);
    }
}

__device__ __forceinline__ void mma_step(const short (*As)[BK], const short (*Bs)[BK],
                                         f32x4 acc[4][4], int wr, int wc, int grp, int lrow) {
    #pragma unroll
    for (int kk = 0; kk < 2; ++kk) {
        s16x8 af[4], bfr[4];
        #pragma unroll
        for (int f = 0; f < 4; ++f)
            af[f] = *(const s16x8*)&As[wr * 64 + f * 16 + lrow][grp * 8 + kk * 32];
        #pragma unroll
        for (int f = 0; f < 4; ++f)
            bfr[f] = *(const s16x8*)&Bs[wc * 64 + f * 16 + lrow][grp * 8 + kk * 32];
        #pragma unroll
        for (int fm = 0; fm < 4; ++fm)
            #pragma unroll
            for (int fn = 0; fn < 4; ++fn)
                acc[fm][fn] = __builtin_amdgcn_mfma_f32_16x16x32_bf16(
                    af[fm], bfr[fn], acc[fm][fn], 0, 0, 0);
    }
}

// ---------------- bf16 MFMA GEMM: C[M,N] = A[M,K] * BT[N,K]^T + bias ----------------
// EPI: 0 = bias -> bf16 Cb; 1 = relu(.+bias) -> bf16 Cb; 2 = .+bias+resid -> float Cf
template<int EPI, int GX, int GY>
__global__ __launch_bounds__(256) void mm_bt(const short* __restrict__ A, int lda,
        const short* __restrict__ BT, int ldb,
        const float* __restrict__ bias, const float* __restrict__ resid,
        float* __restrict__ Cf, short* __restrict__ Cb, int ldc, int K) {
    __shared__ short As[BM][BK];
    __shared__ short Bs[BN][BK];
    const int tid = threadIdx.x;
    const int wave = tid >> 6, lane = tid & 63, grp = lane >> 4, lrow = lane & 15;
    const int wr = wave >> 1, wc = wave & 1;
    int bx, by;
    swz_xslow<GX, GY>(bx, by);
    const int m0 = by * BM, n0 = bx * BN;
    f32x4 acc[4][4];
    #pragma unroll
    for (int a = 0; a < 4; ++a)
        #pragma unroll
        for (int b = 0; b < 4; ++b) acc[a][b] = (f32x4){0.f, 0.f, 0.f, 0.f};
    for (int k0 = 0; k0 < K; k0 += BK) {
        __syncthreads();
        stage_tile(A + (size_t)m0 * lda + k0, lda, &As[0][0], tid);
        stage_tile(BT + (size_t)n0 * ldb + k0, ldb, &Bs[0][0], tid);
        asm volatile("s_waitcnt vmcnt(0)" ::: "memory");
        __syncthreads();
        mma_step(As, Bs, acc, wr, wc, grp, lrow);
    }
    #pragma unroll
    for (int fm = 0; fm < 4; ++fm) {
        #pragma unroll
        for (int i = 0; i < 4; ++i) {
            int row = m0 + wr * 64 + fm * 16 + grp * 4 + i;
            #pragma unroll
            for (int fn = 0; fn < 4; ++fn) {
                int col = n0 + wc * 64 + fn * 16 + lrow;
                float v = acc[fm][fn][i] + bias[col];
                if (EPI == 1) v = fmaxf(v, 0.f);
                if (EPI == 2) {
                    Cf[(size_t)row * ldc + col] = v + resid[(size_t)row * ldc + col];
                } else {
                    Cb[(size_t)row * ldc + col] = f2bf(v);
                }
            }
        }
    }
}

// ---------------- fused Z-sum + masked P (replaces attn_zsum + attn_pmask) ----------------
// grid (32, 64), 256 threads (4 waves, 64x64 per wave = proven mm_bt inner loop).
// Each block: rows [m0, m0+128) x cols [bx*256, bx*256+256) (2 j-tiles of 128).
// For every tile: accumulate run_z = sum exp(s) (full softmax denominator).
// For tiles in the banded window [jbase0, m0+128): additionally write masked
// P = exp(s)*mask (bf16) and Epart row partials — same S, computed once.
__global__ __launch_bounds__(256) void attn_zp(const short* __restrict__ qk,
        const int* __restrict__ sep, const int* __restrict__ begin,
        short* __restrict__ P, float* __restrict__ Epart, float* __restrict__ Zpart) {
    __shared__ short As[BM][BK];
    __shared__ short Bs[BN][BK];
    __shared__ float Ep[BM][2];
    __shared__ float Zs[BM][2];
    const int tid = threadIdx.x;
    const int wave = tid >> 6, lane = tid & 63, grp = lane >> 4, lrow = lane & 15;
    const int wr = wave >> 1, wc = wave & 1;
    int bx, by;
    swz_xslow<32, 64>(bx, by);
    const int m0 = by * BM;
    const int jbase0 = begin[sep[m0]] & ~(BN - 1);
    float run_z[16];
    #pragma unroll
    for (int idx = 0; idx < 16; ++idx) run_z[idx] = 0.f;

    for (int jt = 0; jt < 2; ++jt) {
        const int j0 = bx * 256 + jt * BN;
        f32x4 acc[4][4];
        #pragma unroll
        for (int a = 0; a < 4; ++a)
            #pragma unroll
            for (int b = 0; b < 4; ++b) acc[a][b] = (f32x4){0.f, 0.f, 0.f, 0.f};
        for (int k0 = 0; k0 < DDIM; k0 += BK) {
            __syncthreads();
            stage_tile(qk + (size_t)m0 * 1024 + k0, 1024, &As[0][0], tid);
            stage_tile(qk + (size_t)j0 * 1024 + 512 + k0, 1024, &Bs[0][0], tid);
            asm volatile("s_waitcnt vmcnt(0)" ::: "memory");
            __syncthreads();
            mma_step(As, Bs, acc, wr, wc, grp, lrow);
        }
        const bool inband = (j0 >= jbase0) && (j0 < m0 + BM);
        if (!inband) {
            #pragma unroll
            for (int fm = 0; fm < 4; ++fm)
                #pragma unroll
                for (int i = 0; i < 4; ++i) {
                    float s = 0.f;
                    #pragma unroll
                    for (int fn = 0; fn < 4; ++fn) s += __expf(acc[fm][fn][i]);
                    run_z[fm * 4 + i] += s;
                }
        } else {
            #pragma unroll
            for (int fm = 0; fm < 4; ++fm) {
                #pragma unroll
                for (int i = 0; i < 4; ++i) {
                    const int idx = fm * 4 + i;
                    const int row = m0 + wr * 64 + fm * 16 + grp * 4 + i;
                    const int jsr = begin[sep[row]];
                    float e = 0.f;
                    #pragma unroll
                    for (int fn = 0; fn < 4; ++fn) {
                        const int col = j0 + wc * 64 + fn * 16 + lrow;
                        const float ez = __expf(acc[fm][fn][i]);
                        run_z[idx] += ez;
                        const float p = (col >= jsr && col <= row) ? ez : 0.f;
                        e += p;
                        P[(size_t)row * PW + (col - jbase0)] = f2bf(p);
                    }
                    #pragma unroll
                    for (int off = 1; off < 16; off <<= 1) e += __shfl_xor(e, off, 16);
                    if (lrow == 0) Ep[wr * 64 + fm * 16 + grp * 4 + i][wc] = e;
                }
            }
            __syncthreads();
            if (tid < BM)
                Epart[(size_t)(m0 + tid) * PTILES + ((j0 - jbase0) >> 7)] =
                    Ep[tid][0] + Ep[tid][1];
            // next use of Ep (if jt=0 band, jt=1 band too) is separated by the
            // k-loop's barriers; next use of As/Bs is after the loop-top barrier.
        }
    }

    // Zpart[row][bx] = sum over this block's 256 columns (combine wc halves in LDS)
    #pragma unroll
    for (int idx = 0; idx < 16; ++idx) {
        float z = run_z[idx];
        #pragma unroll
        for (int off = 1; off < 16; off <<= 1) z += __shfl_xor(z, off, 16);
        if (lrow == 0)
            Zs[wr * 64 + (idx >> 2) * 16 + grp * 4 + (idx & 3)][wc] = z;
    }
    __syncthreads();
    if (tid < BM)
        Zpart[(size_t)(m0 + tid) * NPART + bx] = Zs[tid][0] + Zs[tid][1];
}

// invE[r] = 1 / (sum_active Epart + 1e-10 * sum Zpart)
__global__ void inv_combine(const float* __restrict__ Epart, const float* __restrict__ Zpart,
                            const int* __restrict__ sep, const int* __restrict__ begin,
                            float* __restrict__ invE) {
    int r = blockIdx.x * 256 + threadIdx.x;
    if (r >= LTOK) return;
    float z = 0.f;
    #pragma unroll
    for (int c = 0; c < NPART; ++c) z += Zpart[r * NPART + c];
    int m0 = r & ~(BM - 1);
    int jb0 = begin[sep[m0]] & ~(BN - 1);
    int nact = (m0 + BM - jb0) >> 7;     // both multiples of 128
    float e = 0.f;
    for (int x = 0; x < nact; ++x) e += Epart[(size_t)r * PTILES + x];
    invE[r] = 1.f / (e + 1e-10f * z);
}

// ---------------- ctx = (P @ x) * invE, block-banded GEMM ----------------
// grid (4, 64)
__global__ __launch_bounds__(256) void attn_pv(const short* __restrict__ P,
        const short* __restrict__ xbT,
        const int* __restrict__ sep, const int* __restrict__ begin,
        const float* __restrict__ invE, float* __restrict__ ctx) {
    __shared__ short As[BM][BK];
    __shared__ short Bs[BN][BK];
    const int tid = threadIdx.x;
    const int wave = tid >> 6, lane = tid & 63, grp = lane >> 4, lrow = lane & 15;
    const int wr = wave >> 1, wc = wave & 1;
    int bx, by;
    swz_xslow<4, 64>(bx, by);
    const int m0 = by * BM, n0 = bx * BN;
    const int jbase0 = begin[sep[m0]] & ~(BN - 1);
    const int kmax = m0 + BM - jbase0;
    f32x4 acc[4][4];
    #pragma unroll
    for (int a = 0; a < 4; ++a)
        #pragma unroll
        for (int b = 0; b < 4; ++b) acc[a][b] = (f32x4){0.f, 0.f, 0.f, 0.f};
    for (int k0 = 0; k0 < kmax; k0 += BK) {
        __syncthreads();
        stage_tile(P + (size_t)m0 * PW + k0, PW, &As[0][0], tid);
        stage_tile(xbT + (size_t)n0 * LTOK + jbase0 + k0, LTOK, &Bs[0][0], tid);
        asm volatile("s_waitcnt vmcnt(0)" ::: "memory");
        __syncthreads();
        mma_step(As, Bs, acc, wr, wc, grp, lrow);
    }
    #pragma unroll
    for (int fm = 0; fm < 4; ++fm) {
        #pragma unroll
        for (int i = 0; i < 4; ++i) {
            int row = m0 + wr * 64 + fm * 16 + grp * 4 + i;
            float inv = invE[row];
            #pragma unroll
            for (int fn = 0; fn < 4; ++fn) {
                int col = n0 + wc * 64 + fn * 16 + lrow;
                ctx[(size_t)row * DDIM + col] = acc[fm][fn][i] * inv;
            }
        }
    }
}

extern "C" void kernel_launch(void* const* d_in, const int* in_sizes, int n_in,
                              void* d_out, int out_size, void* d_ws, size_t ws_size,
                              hipStream_t stream) {
    const float* xcat = (const float*)d_in[0];
    const int* sep = (const int*)d_in[1];
    const float* Wqkv = (const float*)d_in[2];
    const float* bqkv = (const float*)d_in[3];
    const float* W1 = (const float*)d_in[4];
    const float* b1 = (const float*)d_in[5];
    const float* W2 = (const float*)d_in[6];
    const float* b2 = (const float*)d_in[7];
    float* out = (float*)d_out;

    float* ws = (float*)d_ws;
    float* psum   = ws;                         // 32*512
    float* psumsq = psum + 32 * DDIM;           // 32*512
    float* mu1    = psumsq + 32 * DDIM;         // 512
    float* rstd1  = mu1 + DDIM;
    float* mu2    = rstd1 + DDIM;
    float* rstd2  = mu2 + DDIM;
    float* invE   = rstd2 + DDIM;               // 8192
    float* Zpart  = invE + LTOK;                // 8192*32
    float* Epart  = Zpart + LTOK * NPART;       // 8192*10
    int*   begin  = (int*)(Epart + LTOK * PTILES); // 1024 floats reserved
    short* S0     = (short*)(Epart + (size_t)LTOK * PTILES + 1024);
    short* qk     = S0;                                   // 8192*1024
    short* xbT    = qk    + (size_t)LTOK * 1024;          // 512*8192
    short* lnx    = xbT   + (size_t)DDIM * LTOK;          // 8192*512
    short* lnctx  = lnx   + (size_t)LTOK * DDIM;          // 8192*512
    short* hb     = lnctx + (size_t)LTOK * DDIM;          // 8192*2048
    short* Pbuf   = hb;                                   // 8192*1280 (aliased: dead before hb written)
    short* WqkvT  = hb    + (size_t)LTOK * HDIM;          // 1024*512
    short* W1T    = WqkvT + (size_t)1024 * DDIM;          // 2048*512
    short* W2T    = W1T   + (size_t)HDIM * DDIM;          // 512*2048
    float* ctxF   = (float*)(W2T + (size_t)DDIM * HDIM);  // 8192*512 f32

    // 1) LN1 stats + apply
    ln_stats_partial<<<dim3(32), dim3(512), 0, stream>>>(xcat, psum, psumsq);
    ln_stats_final<<<dim3(1), dim3(512), 0, stream>>>(psum, psumsq, mu1, rstd1);
    ln_apply_bf16<<<dim3(LTOK * DDIM / 4 / 256), dim3(256), 0, stream>>>(xcat, mu1, rstd1, lnx);

    // weight prep (bf16, N-major)
    transpose_w<<<dim3(32, 16), dim3(256), 0, stream>>>(Wqkv, 3 * DDIM, 0, WqkvT, DDIM);
    transpose_w<<<dim3(64, 16), dim3(256), 0, stream>>>(W1, HDIM, 0, W1T, DDIM);
    transpose_w<<<dim3(16, 64), dim3(256), 0, stream>>>(W2, DDIM, 0, W2T, HDIM);

    // 2) qk = ln(x) @ Wqkv[:, :1024] + b  -> bf16 [8192][1024]
    mm_bt<0, 8, 64><<<dim3(8, 64), dim3(256), 0, stream>>>(
        lnx, DDIM, WqkvT, DDIM, bqkv, (const float*)nullptr,
        (float*)nullptr, qk, 1024, DDIM);

    // 3) segment table (+ second output) + xcat transpose
    seg_begin_k<<<dim3(32), dim3(256), 0, stream>>>(sep, begin, out + (size_t)LTOK * DDIM);
    transpose_bf16<<<dim3(16, 256), dim3(256), 0, stream>>>(xcat, xbT);

    // 4+5a) fused: full-row Z + masked P + Epart (single pass over S)
    attn_zp<<<dim3(32, 64), dim3(256), 0, stream>>>(qk, sep, begin, Pbuf, Epart, Zpart);

    // 5b) combine -> ctx = (P @ x) * invE
    inv_combine<<<dim3(32), dim3(256), 0, stream>>>(Epart, Zpart, sep, begin, invE);
    attn_pv<<<dim3(4, 64), dim3(256), 0, stream>>>(Pbuf, xbT, sep, begin, invE, ctxF);

    // 6) LN2 stats + apply
    ln_stats_partial<<<dim3(32), dim3(512), 0, stream>>>(ctxF, psum, psumsq);
    ln_stats_final<<<dim3(1), dim3(512), 0, stream>>>(psum, psumsq, mu2, rstd2);
    ln_apply_bf16<<<dim3(LTOK * DDIM / 4 / 256), dim3(256), 0, stream>>>(ctxF, mu2, rstd2, lnctx);

    // 7) h = relu(ln(ctx) @ W1 + b1)  -> bf16  (overwrites P alias, P already consumed)
    mm_bt<1, 16, 64><<<dim3(16, 64), dim3(256), 0, stream>>>(
        lnctx, DDIM, W1T, DDIM, b1, (const float*)nullptr,
        (float*)nullptr, hb, HDIM, DDIM);

    // 8) out = xcat + h @ W2 + b2
    mm_bt<2, 4, 64><<<dim3(4, 64), dim3(256), 0, stream>>>(
        hb, HDIM, W2T, HDIM, b2, xcat,
        out, (short*)nullptr, DDIM, HDIM);
}